// Round 1
// baseline (1040.818 us; speedup 1.0000x reference)
//
#include <hip/hip_runtime.h>
#include <math.h>

#define D 128
#define BR 64
#define BC 64
#define SEQ 2048
#define NHEADS 32
#define SCALE 0.08838834764831843f  // 1/sqrt(128)

// Flash attention fwd, fp32, causal, with exact softmax max/sum outputs.
// Block: 256 threads (tx = t&15 -> 16 col/dcol groups, ty = t>>4 -> 16 row groups)
// Each thread: S-tile 4x4 (rows ty*4+i, cols tx*4+j), O-tile 4x8 (rows ty*4+i, d = tx*8+jj)
__global__ __launch_bounds__(256, 2) void fa_fwd(
    const float* __restrict__ q,
    const float* __restrict__ k,
    const float* __restrict__ v,
    float* __restrict__ out)
{
    float* out_o = out;                                   // [32][2048][128]
    float* out_m = out + (size_t)NHEADS * SEQ * D;        // [32][2048][8]
    float* out_l = out_m + (size_t)NHEADS * SEQ * 8;      // [32][2048][8]

    // Qs: transposed [d][r], XOR-swizzled columns (conflict-free b128 reads AND ~2-way writes)
    // KVs: phase 1 = K transposed+swizzled [d][c]; phase 2 = V row-major [c][d]
    // Ps: P transposed [c][r]
    __shared__ float Qs[D * BR];     // 32 KB
    __shared__ float KVs[BC * D];    // 32 KB
    __shared__ float Ps[BC * BR];    // 16 KB   -> 80 KB total = 2 blocks/CU

    const int head = blockIdx.y;
    const int it = (int)gridDim.x - 1 - (int)blockIdx.x;  // heavy blocks dispatch first
    const int r0 = it * BR;

    const int t  = (int)threadIdx.x;
    const int tx = t & 15;
    const int ty = t >> 4;

    const float* qh = q + (size_t)head * SEQ * D;
    const float* kh = k + (size_t)head * SEQ * D;
    const float* vh = v + (size_t)head * SEQ * D;

    // ---- load Q tile once: transposed + swizzled ----
    #pragma unroll
    for (int itr = 0; itr < 8; ++itr) {
        int f  = itr * 256 + t;      // float4 index within 64x128 tile
        int r  = f >> 5;             // 0..63
        int d4 = f & 31;             // 0..31
        const float4 val = *(const float4*)(qh + (size_t)(r0 + r) * D + d4 * 4);
        float vv[4] = {val.x, val.y, val.z, val.w};
        #pragma unroll
        for (int u = 0; u < 4; ++u) {
            int d = d4 * 4 + u;
            int col = ((((r >> 2) ^ (d >> 2)) & 15) << 2) | (r & 3);
            Qs[d * 64 + col] = vv[u];
        }
    }

    float m_r[4], l_r[4];
    float acc_o[4][8];
    #pragma unroll
    for (int i = 0; i < 4; ++i) {
        m_r[i] = -INFINITY;
        l_r[i] = 0.f;
        #pragma unroll
        for (int j2 = 0; j2 < 8; ++j2) acc_o[i][j2] = 0.f;
    }

    for (int jt = 0; jt <= it; ++jt) {
        const int c0 = jt * BC;

        __syncthreads();  // KVs safe to overwrite (prev PV done); covers Qs on iter 0

        // ---- load K tile: transposed + swizzled into KVs ----
        #pragma unroll
        for (int itr = 0; itr < 8; ++itr) {
            int f  = itr * 256 + t;
            int c  = f >> 5;
            int d4 = f & 31;
            const float4 val = *(const float4*)(kh + (size_t)(c0 + c) * D + d4 * 4);
            float vv[4] = {val.x, val.y, val.z, val.w};
            #pragma unroll
            for (int u = 0; u < 4; ++u) {
                int d = d4 * 4 + u;
                int col = ((((c >> 2) ^ (d >> 2)) & 15) << 2) | (c & 3);
                KVs[d * 64 + col] = vv[u];
            }
        }
        __syncthreads();

        // ---- S = Q K^T : 4x4 per thread ----
        float acc[4][4];
        #pragma unroll
        for (int i = 0; i < 4; ++i)
            #pragma unroll
            for (int j = 0; j < 4; ++j) acc[i][j] = 0.f;

        #pragma unroll 8
        for (int kk = 0; kk < D; ++kk) {
            const int g = (kk >> 2) & 15;
            const float4 qv = *(const float4*)(Qs  + kk * 64 + (((ty ^ g) & 15) << 2));
            const float4 kv = *(const float4*)(KVs + kk * 64 + (((tx ^ g) & 15) << 2));
            const float qa[4] = {qv.x, qv.y, qv.z, qv.w};
            const float ka[4] = {kv.x, kv.y, kv.z, kv.w};
            #pragma unroll
            for (int i = 0; i < 4; ++i)
                #pragma unroll
                for (int j = 0; j < 4; ++j)
                    acc[i][j] += qa[i] * ka[j];
        }
        __syncthreads();  // done reading K from KVs

        // ---- load V tile row-major [c][d] into KVs (overlaps softmax below) ----
        #pragma unroll
        for (int itr = 0; itr < 8; ++itr) {
            int f  = itr * 256 + t;
            int c  = f >> 5;
            int d4 = f & 31;
            *(float4*)(KVs + c * D + d4 * 4) =
                *(const float4*)(vh + (size_t)(c0 + c) * D + d4 * 4);
        }

        // ---- scale, causal mask, online softmax; write P^T to Ps ----
        #pragma unroll
        for (int i = 0; i < 4; ++i) {
            const int rg = r0 + ty * 4 + i;
            float sv[4];
            float mx = -INFINITY;
            #pragma unroll
            for (int j = 0; j < 4; ++j) {
                float s = acc[i][j] * SCALE;
                if (c0 + tx * 4 + j > rg) s = -INFINITY;
                sv[j] = s;
                mx = fmaxf(mx, s);
            }
            #pragma unroll
            for (int off = 1; off < 16; off <<= 1)
                mx = fmaxf(mx, __shfl_xor(mx, off));
            const float m_new = fmaxf(m_r[i], mx);          // mx finite: col c0 <= rg always valid
            const float alpha = __expf(m_r[i] - m_new);     // first tile: exp(-inf)=0
            float p[4];
            float rs = 0.f;
            #pragma unroll
            for (int j = 0; j < 4; ++j) { p[j] = __expf(sv[j] - m_new); rs += p[j]; }
            #pragma unroll
            for (int off = 1; off < 16; off <<= 1)
                rs += __shfl_xor(rs, off);
            m_r[i] = m_new;
            l_r[i] = l_r[i] * alpha + rs;
            #pragma unroll
            for (int j2 = 0; j2 < 8; ++j2) acc_o[i][j2] *= alpha;
            #pragma unroll
            for (int j = 0; j < 4; ++j)
                Ps[(tx * 4 + j) * 64 + ty * 4 + i] = p[j];
        }
        __syncthreads();  // V + Ps visible

        // ---- O += P V : rows ty*4+i, dcols tx*8..tx*8+7 ----
        #pragma unroll 4
        for (int c = 0; c < BC; ++c) {
            const float4 pv = *(const float4*)(Ps  + c * 64 + ty * 4);
            const float4 v0 = *(const float4*)(KVs + c * D + tx * 8);
            const float4 v1 = *(const float4*)(KVs + c * D + tx * 8 + 4);
            const float pa[4] = {pv.x, pv.y, pv.z, pv.w};
            #pragma unroll
            for (int i = 0; i < 4; ++i) {
                acc_o[i][0] += pa[i] * v0.x;
                acc_o[i][1] += pa[i] * v0.y;
                acc_o[i][2] += pa[i] * v0.z;
                acc_o[i][3] += pa[i] * v0.w;
                acc_o[i][4] += pa[i] * v1.x;
                acc_o[i][5] += pa[i] * v1.y;
                acc_o[i][6] += pa[i] * v1.z;
                acc_o[i][7] += pa[i] * v1.w;
            }
        }
    }

    // ---- epilogue: normalize O, write out + stats (tiled x8) ----
    const size_t obase = (size_t)head * SEQ * D;
    #pragma unroll
    for (int i = 0; i < 4; ++i) {
        const int rg = r0 + ty * 4 + i;
        const float invl = 1.0f / l_r[i];
        float4 o0 = make_float4(acc_o[i][0] * invl, acc_o[i][1] * invl,
                                acc_o[i][2] * invl, acc_o[i][3] * invl);
        float4 o1 = make_float4(acc_o[i][4] * invl, acc_o[i][5] * invl,
                                acc_o[i][6] * invl, acc_o[i][7] * invl);
        *(float4*)(out_o + obase + (size_t)rg * D + tx * 8)     = o0;
        *(float4*)(out_o + obase + (size_t)rg * D + tx * 8 + 4) = o1;
        if (tx < 8) {
            const size_t sb = ((size_t)head * SEQ + rg) * 8 + tx;
            out_m[sb] = m_r[i];
            out_l[sb] = l_r[i];
        }
    }
}

extern "C" void kernel_launch(void* const* d_in, const int* in_sizes, int n_in,
                              void* d_out, int out_size, void* d_ws, size_t ws_size,
                              hipStream_t stream) {
    const float* q = (const float*)d_in[0];
    const float* k = (const float*)d_in[1];
    const float* v = (const float*)d_in[2];
    float* out = (float*)d_out;
    dim3 grid(SEQ / BR, NHEADS);
    fa_fwd<<<grid, dim3(256), 0, stream>>>(q, k, v, out);
}

// Round 2
// 598.054 us; speedup vs baseline: 1.7403x; 1.7403x over previous
//
#include <hip/hip_runtime.h>
#include <math.h>
#include <stdint.h>

#define D_DIM 128
#define SEQ 2048
#define NHEADS 32
#define BR 128
#define BC 64
#define SCALE 0.08838834764831843f  // 1/sqrt(128)

typedef short bf16x8 __attribute__((ext_vector_type(8)));
typedef float f32x4 __attribute__((ext_vector_type(4)));

union Frag { uint32_t u[4]; bf16x8 v; unsigned short s[8]; };

__device__ __forceinline__ uint32_t fbits(float x) { return __builtin_bit_cast(uint32_t, x); }
__device__ __forceinline__ float bbits(uint32_t u) { return __builtin_bit_cast(float, u); }
__device__ __forceinline__ unsigned short bf16_rne(float x) {
    uint32_t u = fbits(x);
    u += 0x7FFFu + ((u >> 16) & 1u);
    return (unsigned short)(u >> 16);
}

// Flash attention fwd, fp32-accuracy via bf16 hi/lo split MFMA.
// Block = 256 thr = 4 waves; each wave: 32 q-rows x full 64-col K tile.
// 16x16x32 bf16 MFMA; verified layouts: A[m=lane&15][k=quad*8+j],
// B[k=quad*8+j][n=lane&15], C/D[row=quad*4+reg][col=lane&15].
__global__ __launch_bounds__(256, 2) void fa_fwd(
    const float* __restrict__ q, const float* __restrict__ k,
    const float* __restrict__ v, float* __restrict__ out)
{
    // 16B-chunk XOR swizzles throughout -> <=2-way conflicts. 80KB total.
    __shared__ __align__(16) unsigned short Khs[64 * 128];  // K hi, [n][k]
    __shared__ __align__(16) unsigned short Kls[64 * 128];  // K lo
    __shared__ __align__(16) unsigned short Vhs[128 * 64];  // V^T hi, [d][c]
    __shared__ __align__(16) unsigned short Vls[128 * 64];  // V^T lo
    __shared__ __align__(16) unsigned short Pbs[128 * 64];  // P hi, [row][c]

    // XCD-affine: heads 4c..4c+3 on XCD c (heuristic), heavy q-tiles first.
    const int x = blockIdx.x;
    const int h  = (x & 7) * 4 + (x >> 7);
    const int it = 15 - ((x >> 3) & 15);

    const int t    = (int)threadIdx.x;
    const int wb   = t >> 6;
    const int lane = t & 63;
    const int ln   = lane & 15;
    const int qd   = lane >> 4;

    const float* qh = q + (size_t)h * SEQ * D_DIM;
    const float* kh = k + (size_t)h * SEQ * D_DIM;
    const float* vh = v + (size_t)h * SEQ * D_DIM;
    float* out_o = out;
    float* out_m = out + (size_t)NHEADS * SEQ * D_DIM;
    float* out_l = out_m + (size_t)NHEADS * SEQ * 8;

    const int qrow0 = it * BR + wb * 32;

    // ---- Q fragments (hi/lo) resident in registers: 64 VGPRs ----
    Frag Qh[2][4], Ql[2][4];
    #pragma unroll
    for (int mt = 0; mt < 2; ++mt) {
        const float* qp = qh + (size_t)(qrow0 + mt * 16 + ln) * D_DIM;
        #pragma unroll
        for (int kc = 0; kc < 4; ++kc) {
            const int kb = kc * 32 + qd * 8;
            float e[8];
            *(float4*)(e)     = *(const float4*)(qp + kb);
            *(float4*)(e + 4) = *(const float4*)(qp + kb + 4);
            #pragma unroll
            for (int j = 0; j < 4; ++j) {
                float a = e[2 * j], b = e[2 * j + 1];
                uint32_t ua = fbits(a) & 0xFFFF0000u, ub = fbits(b) & 0xFFFF0000u;
                float la = a - bbits(ua), lb = b - bbits(ub);
                Qh[mt][kc].u[j] = (ua >> 16) | ub;
                Ql[mt][kc].u[j] = (fbits(la) >> 16) | (fbits(lb) & 0xFFFF0000u);
            }
        }
    }

    f32x4 accO[2][8];
    float m_r[2][4], l_r[2][4];
    #pragma unroll
    for (int mt = 0; mt < 2; ++mt) {
        #pragma unroll
        for (int nd = 0; nd < 8; ++nd) accO[mt][nd] = (f32x4){0.f, 0.f, 0.f, 0.f};
        #pragma unroll
        for (int r = 0; r < 4; ++r) { m_r[mt][r] = -INFINITY; l_r[mt][r] = 0.f; }
    }

    const int jt_end = 2 * it + 1;
    for (int jt = 0; jt <= jt_end; ++jt) {
        const int c0 = jt * BC;
        __syncthreads();  // prev iter's K/V reads done

        // ---- stage K tile: [64][128] fp32 -> hi/lo bf16, row-swizzled ----
        #pragma unroll
        for (int itr = 0; itr < 8; ++itr) {
            int f = itr * 256 + t;
            int row = f >> 5, d4 = f & 31;
            float e[4];
            *(float4*)e = *(const float4*)(kh + (size_t)(c0 + row) * D_DIM + d4 * 4);
            uint32_t hp[2], lp[2];
            #pragma unroll
            for (int j = 0; j < 2; ++j) {
                float a = e[2 * j], b = e[2 * j + 1];
                uint32_t ua = fbits(a) & 0xFFFF0000u, ub = fbits(b) & 0xFFFF0000u;
                float la = a - bbits(ua), lb = b - bbits(ub);
                hp[j] = (ua >> 16) | ub;
                lp[j] = (fbits(la) >> 16) | (fbits(lb) & 0xFFFF0000u);
            }
            int off = row * 128 + (((d4 >> 1) ^ (row & 7)) * 8) + (d4 & 1) * 4;
            *(uint2*)(Khs + off) = make_uint2(hp[0], hp[1]);
            *(uint2*)(Kls + off) = make_uint2(lp[0], lp[1]);
        }
        // ---- stage V transposed: lane gathers a d-column of 8 c's ----
        #pragma unroll
        for (int uu = 0; uu < 4; ++uu) {
            int ug = wb * 4 + uu;
            int cc = ug >> 1, dh = ug & 1;
            int d = dh * 64 + lane;
            Frag fh, fl;
            #pragma unroll
            for (int j = 0; j < 8; j += 2) {
                float a = vh[(size_t)(c0 + cc * 8 + j) * D_DIM + d];      // 256B coalesced
                float b = vh[(size_t)(c0 + cc * 8 + j + 1) * D_DIM + d];
                uint32_t ua = fbits(a) & 0xFFFF0000u, ub = fbits(b) & 0xFFFF0000u;
                float la = a - bbits(ua), lb = b - bbits(ub);
                fh.u[j >> 1] = (ua >> 16) | ub;
                fl.u[j >> 1] = (fbits(la) >> 16) | (fbits(lb) & 0xFFFF0000u);
            }
            int off = d * 64 + ((cc ^ (d & 7)) * 8);
            *(bf16x8*)(Vhs + off) = fh.v;
            *(bf16x8*)(Vls + off) = fl.v;
        }
        __syncthreads();

        if (c0 <= qrow0 + 31) {  // wave-uniform: skip tiles fully above causal band
            // ---- S = Q K^T (split-3: hh + hl + lh) ----
            f32x4 accS[2][4];
            #pragma unroll
            for (int mt = 0; mt < 2; ++mt)
                #pragma unroll
                for (int nt = 0; nt < 4; ++nt) accS[mt][nt] = (f32x4){0.f, 0.f, 0.f, 0.f};
            #pragma unroll
            for (int kc = 0; kc < 4; ++kc) {
                #pragma unroll
                for (int ntp = 0; ntp < 4; ntp += 2) {
                    Frag Bh[2], Bl[2];
                    #pragma unroll
                    for (int e2 = 0; e2 < 2; ++e2) {
                        int n = (ntp + e2) * 16 + ln;
                        int off = n * 128 + (((kc * 4 + qd) ^ (n & 7)) * 8);
                        Bh[e2].v = *(const bf16x8*)(Khs + off);
                        Bl[e2].v = *(const bf16x8*)(Kls + off);
                    }
                    #pragma unroll
                    for (int mt = 0; mt < 2; ++mt)
                        #pragma unroll
                        for (int e2 = 0; e2 < 2; ++e2) {
                            f32x4 c = accS[mt][ntp + e2];
                            c = __builtin_amdgcn_mfma_f32_16x16x32_bf16(Qh[mt][kc].v, Bh[e2].v, c, 0, 0, 0);
                            c = __builtin_amdgcn_mfma_f32_16x16x32_bf16(Qh[mt][kc].v, Bl[e2].v, c, 0, 0, 0);
                            c = __builtin_amdgcn_mfma_f32_16x16x32_bf16(Ql[mt][kc].v, Bh[e2].v, c, 0, 0, 0);
                            accS[mt][ntp + e2] = c;
                        }
                }
            }
            // ---- online softmax (exact m/l in fp32) ----
            #pragma unroll
            for (int mt = 0; mt < 2; ++mt) {
                #pragma unroll
                for (int r = 0; r < 4; ++r) {
                    const int rowg = qrow0 + mt * 16 + qd * 4 + r;
                    float sv[4], mx = -INFINITY;
                    #pragma unroll
                    for (int nt = 0; nt < 4; ++nt) {
                        float s = accS[mt][nt][r] * SCALE;
                        if (c0 + nt * 16 + ln > rowg) s = -INFINITY;  // causal
                        sv[nt] = s; mx = fmaxf(mx, s);
                    }
                    #pragma unroll
                    for (int off = 1; off < 16; off <<= 1) mx = fmaxf(mx, __shfl_xor(mx, off));
                    const float mnew = fmaxf(m_r[mt][r], mx);
                    const float alpha = __expf(m_r[mt][r] - mnew);  // first tile: exp(-inf)=0
                    float p[4], rs = 0.f;
                    #pragma unroll
                    for (int nt = 0; nt < 4; ++nt) { p[nt] = __expf(sv[nt] - mnew); rs += p[nt]; }
                    #pragma unroll
                    for (int off = 1; off < 16; off <<= 1) rs += __shfl_xor(rs, off);
                    m_r[mt][r] = mnew;
                    l_r[mt][r] = l_r[mt][r] * alpha + rs;
                    #pragma unroll
                    for (int nd = 0; nd < 8; ++nd) accO[mt][nd][r] *= alpha;
                    const int R = wb * 32 + mt * 16 + qd * 4 + r;  // intra-wave P region
                    #pragma unroll
                    for (int nt = 0; nt < 4; ++nt) {
                        int c = nt * 16 + ln;
                        Pbs[R * 64 + (((c >> 3) ^ (R & 7)) * 8) + (c & 7)] = bf16_rne(p[nt]);
                    }
                }
            }
            // ---- O += P (V_hi + V_lo) ----
            #pragma unroll
            for (int kc2 = 0; kc2 < 2; ++kc2) {
                Frag Pf[2];
                #pragma unroll
                for (int mt = 0; mt < 2; ++mt) {
                    int R = wb * 32 + mt * 16 + ln;
                    Pf[mt].v = *(const bf16x8*)(Pbs + R * 64 + (((kc2 * 4 + qd) ^ (R & 7)) * 8));
                }
                #pragma unroll
                for (int nd = 0; nd < 8; ++nd) {
                    int dcol = nd * 16 + ln;
                    int voff = dcol * 64 + (((kc2 * 4 + qd) ^ (dcol & 7)) * 8);
                    Frag Vh2, Vl2;
                    Vh2.v = *(const bf16x8*)(Vhs + voff);
                    Vl2.v = *(const bf16x8*)(Vls + voff);
                    #pragma unroll
                    for (int mt = 0; mt < 2; ++mt) {
                        f32x4 c = accO[mt][nd];
                        c = __builtin_amdgcn_mfma_f32_16x16x32_bf16(Pf[mt].v, Vh2.v, c, 0, 0, 0);
                        c = __builtin_amdgcn_mfma_f32_16x16x32_bf16(Pf[mt].v, Vl2.v, c, 0, 0, 0);
                        accO[mt][nd] = c;
                    }
                }
            }
        }
    }

    // ---- epilogue: O/l, stats tiled x8 ----
    #pragma unroll
    for (int mt = 0; mt < 2; ++mt) {
        #pragma unroll
        for (int r = 0; r < 4; ++r) {
            const int rowg = qrow0 + mt * 16 + qd * 4 + r;
            const float invl = 1.0f / l_r[mt][r];
            float* op = out_o + (size_t)h * SEQ * D_DIM + (size_t)rowg * D_DIM;
            #pragma unroll
            for (int nd = 0; nd < 8; ++nd) op[nd * 16 + ln] = accO[mt][nd][r] * invl;
            if (ln < 8) {
                size_t sb = ((size_t)h * SEQ + rowg) * 8 + ln;
                out_m[sb] = m_r[mt][r];
                out_l[sb] = l_r[mt][r];
            }
        }
    }
}

extern "C" void kernel_launch(void* const* d_in, const int* in_sizes, int n_in,
                              void* d_out, int out_size, void* d_ws, size_t ws_size,
                              hipStream_t stream) {
    const float* q = (const float*)d_in[0];
    const float* k = (const float*)d_in[1];
    const float* v = (const float*)d_in[2];
    fa_fwd<<<dim3(512), dim3(256), 0, stream>>>(q, k, v, (float*)d_out);
}

// Round 3
// 503.338 us; speedup vs baseline: 2.0678x; 1.1882x over previous
//
#include <hip/hip_runtime.h>
#include <math.h>
#include <stdint.h>

#define D_DIM 128
#define SEQ 2048
#define NHEADS 32
#define BR 128
#define BC 64
#define SCALE 0.08838834764831843f  // 1/sqrt(128)

typedef short bf16x8 __attribute__((ext_vector_type(8)));
typedef float f32x4 __attribute__((ext_vector_type(4)));

union Frag { uint32_t u[4]; bf16x8 v; unsigned short s[8]; };

__device__ __forceinline__ uint32_t fbits(float x) { return __builtin_bit_cast(uint32_t, x); }
__device__ __forceinline__ float bbits(uint32_t u) { return __builtin_bit_cast(float, u); }
__device__ __forceinline__ unsigned short bf16_rne(float x) {
    uint32_t u = fbits(x);
    u += 0x7FFFu + ((u >> 16) & 1u);
    return (unsigned short)(u >> 16);
}

// Flash attention fwd, fp32-accuracy via bf16 hi/lo split MFMA.
// Block = 256 thr = 4 waves; each wave: 32 q-rows x full 64-col K tile.
// 16x16x32 bf16 MFMA; verified layouts: A[m=lane&15][k=quad*8+j],
// B[k=quad*8+j][n=lane&15], C/D[row=quad*4+reg][col=lane&15].
// R3: complementary (it, 15-it) CU pairing + K register-prefetch pipeline,
//     V loads issued ahead of K-convert so their latency is covered.
__global__ __launch_bounds__(256, 2) void fa_fwd(
    const float* __restrict__ q, const float* __restrict__ k,
    const float* __restrict__ v, float* __restrict__ out)
{
    // 16B-chunk XOR swizzles throughout -> <=2-way conflicts. 80KB total = 2 blocks/CU.
    __shared__ __align__(16) unsigned short Khs[64 * 128];  // K hi, [n][k]
    __shared__ __align__(16) unsigned short Kls[64 * 128];  // K lo
    __shared__ __align__(16) unsigned short Vhs[128 * 64];  // V^T hi, [d][c]
    __shared__ __align__(16) unsigned short Vls[128 * 64];  // V^T lo
    __shared__ __align__(16) unsigned short Pbs[128 * 64];  // P bf16, [row][c]

    // All 512 blocks co-resident (2/CU). Within an XCD, blocks y and y+32
    // share a CU (breadth-first fill) -> make their work complementary:
    // it(y) + it(y+32) = 15  => every CU does exactly 34 tile-iters.
    const int x = blockIdx.x;
    const int y = x >> 3;
    const int s_idx = y & 15;
    const int h = (x & 7) * 4 + (y >> 4);
    const int it = (y < 32) ? (15 - s_idx) : s_idx;

    const int t    = (int)threadIdx.x;
    const int wb   = t >> 6;
    const int lane = t & 63;
    const int ln   = lane & 15;
    const int qd   = lane >> 4;

    const float* qh = q + (size_t)h * SEQ * D_DIM;
    const float* kh = k + (size_t)h * SEQ * D_DIM;
    const float* vh = v + (size_t)h * SEQ * D_DIM;
    float* out_o = out;
    float* out_m = out + (size_t)NHEADS * SEQ * D_DIM;
    float* out_l = out_m + (size_t)NHEADS * SEQ * 8;

    const int qrow0 = it * BR + wb * 32;

    // ---- Q fragments (hi/lo) resident in registers: 64 VGPRs ----
    Frag Qh[2][4], Ql[2][4];
    #pragma unroll
    for (int mt = 0; mt < 2; ++mt) {
        const float* qp = qh + (size_t)(qrow0 + mt * 16 + ln) * D_DIM;
        #pragma unroll
        for (int kc = 0; kc < 4; ++kc) {
            const int kb = kc * 32 + qd * 8;
            float e[8];
            *(float4*)(e)     = *(const float4*)(qp + kb);
            *(float4*)(e + 4) = *(const float4*)(qp + kb + 4);
            #pragma unroll
            for (int j = 0; j < 4; ++j) {
                float a = e[2 * j], b = e[2 * j + 1];
                uint32_t ua = fbits(a) & 0xFFFF0000u, ub = fbits(b) & 0xFFFF0000u;
                float la = a - bbits(ua), lb = b - bbits(ub);
                Qh[mt][kc].u[j] = (ua >> 16) | ub;
                Ql[mt][kc].u[j] = (fbits(la) >> 16) | (fbits(lb) & 0xFFFF0000u);
            }
        }
    }

    f32x4 accO[2][8];
    float m_r[2][4], l_r[2][4];
    #pragma unroll
    for (int mt = 0; mt < 2; ++mt) {
        #pragma unroll
        for (int nd = 0; nd < 8; ++nd) accO[mt][nd] = (f32x4){0.f, 0.f, 0.f, 0.f};
        #pragma unroll
        for (int r = 0; r < 4; ++r) { m_r[mt][r] = -INFINITY; l_r[mt][r] = 0.f; }
    }

    // ---- K tile register prefetch (software pipeline, +32 VGPRs) ----
    const int krow = (t * 8) >> 8;          // == (itr*256+t)>>5 pattern, see below
    float4 kpre[8];
    {
        #pragma unroll
        for (int itr = 0; itr < 8; ++itr) {
            int f = itr * 256 + t;
            int row = f >> 5, d4 = f & 31;
            kpre[itr] = *(const float4*)(kh + (size_t)row * D_DIM + d4 * 4);
        }
    }

    const int jt_end = 2 * it + 1;
    for (int jt = 0; jt <= jt_end; ++jt) {
        const int c0 = jt * BC;
        __syncthreads();  // prev iter's LDS reads done -> safe to overwrite

        // ---- issue V gather loads first (latency hidden by K convert) ----
        float vtmp[4][8];
        #pragma unroll
        for (int uu = 0; uu < 4; ++uu) {
            int ug = wb * 4 + uu;
            int cc = ug >> 1, dh = ug & 1;
            int d = dh * 64 + lane;
            #pragma unroll
            for (int j = 0; j < 8; ++j)
                vtmp[uu][j] = vh[(size_t)(c0 + cc * 8 + j) * D_DIM + d];  // 256B coalesced
        }

        // ---- stage K tile from prefetch regs: fp32 -> hi/lo bf16, swizzled ----
        #pragma unroll
        for (int itr = 0; itr < 8; ++itr) {
            int f = itr * 256 + t;
            int row = f >> 5, d4 = f & 31;
            float e[4];
            *(float4*)e = kpre[itr];
            uint32_t hp[2], lp[2];
            #pragma unroll
            for (int j = 0; j < 2; ++j) {
                float a = e[2 * j], b = e[2 * j + 1];
                uint32_t ua = fbits(a) & 0xFFFF0000u, ub = fbits(b) & 0xFFFF0000u;
                float la = a - bbits(ua), lb = b - bbits(ub);
                hp[j] = (ua >> 16) | ub;
                lp[j] = (fbits(la) >> 16) | (fbits(lb) & 0xFFFF0000u);
            }
            int off = row * 128 + (((d4 >> 1) ^ (row & 7)) * 8) + (d4 & 1) * 4;
            *(uint2*)(Khs + off) = make_uint2(hp[0], hp[1]);
            *(uint2*)(Kls + off) = make_uint2(lp[0], lp[1]);
        }

        // ---- prefetch next K tile (in flight through all of compute) ----
        if (jt < jt_end) {
            #pragma unroll
            for (int itr = 0; itr < 8; ++itr) {
                int f = itr * 256 + t;
                int row = f >> 5, d4 = f & 31;
                kpre[itr] = *(const float4*)(kh + (size_t)(c0 + BC + row) * D_DIM + d4 * 4);
            }
        }

        // ---- stage V transposed from gathered regs ----
        #pragma unroll
        for (int uu = 0; uu < 4; ++uu) {
            int ug = wb * 4 + uu;
            int cc = ug >> 1, dh = ug & 1;
            int d = dh * 64 + lane;
            Frag fh, fl;
            #pragma unroll
            for (int j = 0; j < 8; j += 2) {
                float a = vtmp[uu][j], b = vtmp[uu][j + 1];
                uint32_t ua = fbits(a) & 0xFFFF0000u, ub = fbits(b) & 0xFFFF0000u;
                float la = a - bbits(ua), lb = b - bbits(ub);
                fh.u[j >> 1] = (ua >> 16) | ub;
                fl.u[j >> 1] = (fbits(la) >> 16) | (fbits(lb) & 0xFFFF0000u);
            }
            int off = d * 64 + ((cc ^ (d & 7)) * 8);
            *(bf16x8*)(Vhs + off) = fh.v;
            *(bf16x8*)(Vls + off) = fl.v;
        }
        __syncthreads();

        if (c0 <= qrow0 + 31) {  // wave-uniform: skip tiles fully above causal band
            // ---- S = Q K^T (split-3: hh + hl + lh) ----
            f32x4 accS[2][4];
            #pragma unroll
            for (int mt = 0; mt < 2; ++mt)
                #pragma unroll
                for (int nt = 0; nt < 4; ++nt) accS[mt][nt] = (f32x4){0.f, 0.f, 0.f, 0.f};
            #pragma unroll
            for (int kc = 0; kc < 4; ++kc) {
                #pragma unroll
                for (int ntp = 0; ntp < 4; ntp += 2) {
                    Frag Bh[2], Bl[2];
                    #pragma unroll
                    for (int e2 = 0; e2 < 2; ++e2) {
                        int n = (ntp + e2) * 16 + ln;
                        int off = n * 128 + (((kc * 4 + qd) ^ (n & 7)) * 8);
                        Bh[e2].v = *(const bf16x8*)(Khs + off);
                        Bl[e2].v = *(const bf16x8*)(Kls + off);
                    }
                    #pragma unroll
                    for (int mt = 0; mt < 2; ++mt)
                        #pragma unroll
                        for (int e2 = 0; e2 < 2; ++e2) {
                            f32x4 c = accS[mt][ntp + e2];
                            c = __builtin_amdgcn_mfma_f32_16x16x32_bf16(Qh[mt][kc].v, Bh[e2].v, c, 0, 0, 0);
                            c = __builtin_amdgcn_mfma_f32_16x16x32_bf16(Qh[mt][kc].v, Bl[e2].v, c, 0, 0, 0);
                            c = __builtin_amdgcn_mfma_f32_16x16x32_bf16(Ql[mt][kc].v, Bh[e2].v, c, 0, 0, 0);
                            accS[mt][ntp + e2] = c;
                        }
                }
            }
            // ---- online softmax (exact m/l in fp32) ----
            #pragma unroll
            for (int mt = 0; mt < 2; ++mt) {
                #pragma unroll
                for (int r = 0; r < 4; ++r) {
                    const int rowg = qrow0 + mt * 16 + qd * 4 + r;
                    float sv[4], mx = -INFINITY;
                    #pragma unroll
                    for (int nt = 0; nt < 4; ++nt) {
                        float s = accS[mt][nt][r] * SCALE;
                        if (c0 + nt * 16 + ln > rowg) s = -INFINITY;  // causal
                        sv[nt] = s; mx = fmaxf(mx, s);
                    }
                    #pragma unroll
                    for (int off = 1; off < 16; off <<= 1) mx = fmaxf(mx, __shfl_xor(mx, off));
                    const float mnew = fmaxf(m_r[mt][r], mx);
                    const float alpha = __expf(m_r[mt][r] - mnew);  // first tile: exp(-inf)=0
                    float p[4], rs = 0.f;
                    #pragma unroll
                    for (int nt = 0; nt < 4; ++nt) { p[nt] = __expf(sv[nt] - mnew); rs += p[nt]; }
                    #pragma unroll
                    for (int off = 1; off < 16; off <<= 1) rs += __shfl_xor(rs, off);
                    m_r[mt][r] = mnew;
                    l_r[mt][r] = l_r[mt][r] * alpha + rs;
                    #pragma unroll
                    for (int nd = 0; nd < 8; ++nd) accO[mt][nd][r] *= alpha;
                    const int R = wb * 32 + mt * 16 + qd * 4 + r;  // intra-wave P region
                    #pragma unroll
                    for (int nt = 0; nt < 4; ++nt) {
                        int c = nt * 16 + ln;
                        Pbs[R * 64 + (((c >> 3) ^ (R & 7)) * 8) + (c & 7)] = bf16_rne(p[nt]);
                    }
                }
            }
            // ---- O += P (V_hi + V_lo) ----
            #pragma unroll
            for (int kc2 = 0; kc2 < 2; ++kc2) {
                Frag Pf[2];
                #pragma unroll
                for (int mt = 0; mt < 2; ++mt) {
                    int R = wb * 32 + mt * 16 + ln;
                    Pf[mt].v = *(const bf16x8*)(Pbs + R * 64 + (((kc2 * 4 + qd) ^ (R & 7)) * 8));
                }
                #pragma unroll
                for (int nd = 0; nd < 8; ++nd) {
                    int dcol = nd * 16 + ln;
                    int voff = dcol * 64 + (((kc2 * 4 + qd) ^ (dcol & 7)) * 8);
                    Frag Vh2, Vl2;
                    Vh2.v = *(const bf16x8*)(Vhs + voff);
                    Vl2.v = *(const bf16x8*)(Vls + voff);
                    #pragma unroll
                    for (int mt = 0; mt < 2; ++mt) {
                        f32x4 c = accO[mt][nd];
                        c = __builtin_amdgcn_mfma_f32_16x16x32_bf16(Pf[mt].v, Vh2.v, c, 0, 0, 0);
                        c = __builtin_amdgcn_mfma_f32_16x16x32_bf16(Pf[mt].v, Vl2.v, c, 0, 0, 0);
                        accO[mt][nd] = c;
                    }
                }
            }
        }
    }

    // ---- epilogue: O/l, stats tiled x8 ----
    #pragma unroll
    for (int mt = 0; mt < 2; ++mt) {
        #pragma unroll
        for (int r = 0; r < 4; ++r) {
            const int rowg = qrow0 + mt * 16 + qd * 4 + r;
            const float invl = 1.0f / l_r[mt][r];
            float* op = out_o + (size_t)h * SEQ * D_DIM + (size_t)rowg * D_DIM;
            #pragma unroll
            for (int nd = 0; nd < 8; ++nd) op[nd * 16 + ln] = accO[mt][nd][r] * invl;
            if (ln < 8) {
                size_t sb = ((size_t)h * SEQ + rowg) * 8 + ln;
                out_m[sb] = m_r[mt][r];
                out_l[sb] = l_r[mt][r];
            }
        }
    }
}

extern "C" void kernel_launch(void* const* d_in, const int* in_sizes, int n_in,
                              void* d_out, int out_size, void* d_ws, size_t ws_size,
                              hipStream_t stream) {
    const float* q = (const float*)d_in[0];
    const float* k = (const float*)d_in[1];
    const float* v = (const float*)d_in[2];
    fa_fwd<<<dim3(512), dim3(256), 0, stream>>>(q, k, v, (float*)d_out);
}

// Round 4
// 502.881 us; speedup vs baseline: 2.0697x; 1.0009x over previous
//
#include <hip/hip_runtime.h>
#include <math.h>
#include <stdint.h>

#define D_DIM 128
#define SEQ 2048
#define NHEADS 32
#define BR 128
#define BC 64
#define SCALE 0.08838834764831843f  // 1/sqrt(128)

typedef short bf16x8 __attribute__((ext_vector_type(8)));
typedef float f32x4 __attribute__((ext_vector_type(4)));

union Frag { uint32_t u[4]; bf16x8 v; unsigned short s[8]; };

__device__ __forceinline__ uint32_t fbits(float x) { return __builtin_bit_cast(uint32_t, x); }
__device__ __forceinline__ float bbits(uint32_t u) { return __builtin_bit_cast(float, u); }
__device__ __forceinline__ unsigned short bf16_rne(float x) {
    uint32_t u = fbits(x);
    u += 0x7FFFu + ((u >> 16) & 1u);
    return (unsigned short)(u >> 16);
}
// hi = truncate-to-bf16(x) (exact residual), lo = truncate-to-bf16(x - hi).
// Packs pairs (a=even elt -> low16, b=odd elt -> high16).
__device__ __forceinline__ void split2(float a, float b, uint32_t& hp, uint32_t& lp) {
    uint32_t ua = fbits(a) & 0xFFFF0000u, ub = fbits(b) & 0xFFFF0000u;
    float la = a - bbits(ua), lb = b - bbits(ub);
    hp = (ua >> 16) | ub;
    lp = (fbits(la) >> 16) | (fbits(lb) & 0xFFFF0000u);
}

// ---------------- pre-pass: convert K -> hi/lo bf16 [h][s][d], V -> V^T hi/lo [h][d][s] ----------------
__global__ __launch_bounds__(256) void cvt_kv(
    const float* __restrict__ k, const float* __restrict__ v,
    unsigned short* __restrict__ Khi, unsigned short* __restrict__ Klo,
    unsigned short* __restrict__ Vthi, unsigned short* __restrict__ Vtlo)
{
    const int b = blockIdx.x, t = (int)threadIdx.x;
    if (b < 8192) {
        // K elementwise: 8192 blocks x 256 thr x 4 floats = 32*2048*128 exactly
        size_t g4 = (size_t)b * 256 + t;
        float4 e = *(const float4*)(k + g4 * 4);
        uint32_t h0, l0, h1, l1;
        split2(e.x, e.y, h0, l0);
        split2(e.z, e.w, h1, l1);
        *(uint2*)(Khi + g4 * 4) = make_uint2(h0, h1);
        *(uint2*)(Klo + g4 * 4) = make_uint2(l0, l1);
    } else {
        // V transpose-convert: 2048 blocks = 32 heads x 32 s-tiles x 2 d-halves; 64x64 tile
        __shared__ float Ls[64 * 65];
        const int b2 = b - 8192;
        const int h = b2 >> 6, rem = b2 & 63, st = rem & 31, dt = rem >> 5;
        const int s0 = st * 64, d0 = dt * 64;
        const float* vp = v + (size_t)h * SEQ * D_DIM;
        #pragma unroll
        for (int it = 0; it < 4; ++it) {
            int f = it * 256 + t, row = f >> 4, c4 = f & 15;
            float4 e = *(const float4*)(vp + (size_t)(s0 + row) * D_DIM + d0 + c4 * 4);
            float* lp = Ls + row * 65 + c4 * 4;
            lp[0] = e.x; lp[1] = e.y; lp[2] = e.z; lp[3] = e.w;
        }
        __syncthreads();
        const int dl = t >> 2, sc = (t & 3) * 16;
        uint32_t hp[8], lp[8];
        #pragma unroll
        for (int j = 0; j < 16; j += 2) {
            float a = Ls[(sc + j) * 65 + dl];
            float c = Ls[(sc + j + 1) * 65 + dl];
            split2(a, c, hp[j >> 1], lp[j >> 1]);
        }
        size_t ob = ((size_t)h * D_DIM + d0 + dl) * SEQ + s0 + sc;
        *(uint4*)(Vthi + ob)     = make_uint4(hp[0], hp[1], hp[2], hp[3]);
        *(uint4*)(Vthi + ob + 8) = make_uint4(hp[4], hp[5], hp[6], hp[7]);
        *(uint4*)(Vtlo + ob)     = make_uint4(lp[0], lp[1], lp[2], lp[3]);
        *(uint4*)(Vtlo + ob + 8) = make_uint4(lp[4], lp[5], lp[6], lp[7]);
    }
}

// ---------------- main attention kernel: staging = pure bf16 vector loads + ds_write_b128 ----------------
// Block = 256 thr = 4 waves; each wave: 32 q-rows x full 64-col K tile.
// 16x16x32 bf16 MFMA; layouts: A[m=lane&15][k=quad*8+j], B[k=quad*8+j][n=lane&15],
// C/D[row=quad*4+reg][col=lane&15].
__global__ __launch_bounds__(256, 2) void fa_fwd2(
    const float* __restrict__ q,
    const unsigned short* __restrict__ Khi, const unsigned short* __restrict__ Klo,
    const unsigned short* __restrict__ Vthi, const unsigned short* __restrict__ Vtlo,
    float* __restrict__ out)
{
    // 16B-chunk XOR swizzles -> <=2-way conflicts. 80KB total = 2 blocks/CU.
    __shared__ __align__(16) unsigned short Khs[64 * 128];  // K hi, [n][k]
    __shared__ __align__(16) unsigned short Kls[64 * 128];  // K lo
    __shared__ __align__(16) unsigned short Vhs[128 * 64];  // V^T hi, [d][c]
    __shared__ __align__(16) unsigned short Vls[128 * 64];  // V^T lo
    __shared__ __align__(16) unsigned short Pbs[128 * 64];  // P bf16, [row][c]

    // Complementary CU pairing: blocks y and y+32 share a CU -> it(y)+it(y+32)=15,
    // every CU does exactly 34 tile-iters.
    const int x = blockIdx.x;
    const int y = x >> 3;
    const int s_idx = y & 15;
    const int h = (x & 7) * 4 + (y >> 4);
    const int it = (y < 32) ? (15 - s_idx) : s_idx;

    const int t    = (int)threadIdx.x;
    const int wb   = t >> 6;
    const int lane = t & 63;
    const int ln   = lane & 15;
    const int qd   = lane >> 4;

    const float* qh = q + (size_t)h * SEQ * D_DIM;
    const unsigned short* KhiH = Khi + (size_t)h * SEQ * D_DIM;
    const unsigned short* KloH = Klo + (size_t)h * SEQ * D_DIM;
    const unsigned short* VthiH = Vthi + (size_t)h * D_DIM * SEQ;
    const unsigned short* VtloH = Vtlo + (size_t)h * D_DIM * SEQ;
    float* out_o = out;
    float* out_m = out + (size_t)NHEADS * SEQ * D_DIM;
    float* out_l = out_m + (size_t)NHEADS * SEQ * 8;

    const int qrow0 = it * BR + wb * 32;

    // ---- Q fragments (hi/lo) in registers: 64 VGPRs ----
    Frag Qh[2][4], Ql[2][4];
    #pragma unroll
    for (int mt = 0; mt < 2; ++mt) {
        const float* qp = qh + (size_t)(qrow0 + mt * 16 + ln) * D_DIM;
        #pragma unroll
        for (int kc = 0; kc < 4; ++kc) {
            const int kb = kc * 32 + qd * 8;
            float e[8];
            *(float4*)(e)     = *(const float4*)(qp + kb);
            *(float4*)(e + 4) = *(const float4*)(qp + kb + 4);
            #pragma unroll
            for (int j = 0; j < 4; ++j)
                split2(e[2 * j], e[2 * j + 1], Qh[mt][kc].u[j], Ql[mt][kc].u[j]);
        }
    }

    f32x4 accO[2][8];
    float m_r[2][4], l_r[2][4];
    #pragma unroll
    for (int mt = 0; mt < 2; ++mt) {
        #pragma unroll
        for (int nd = 0; nd < 8; ++nd) accO[mt][nd] = (f32x4){0.f, 0.f, 0.f, 0.f};
        #pragma unroll
        for (int r = 0; r < 4; ++r) { m_r[mt][r] = -INFINITY; l_r[mt][r] = 0.f; }
    }

    const int jt_end = 2 * it + 1;
    for (int jt = 0; jt <= jt_end; ++jt) {
        const int c0 = jt * BC;
        __syncthreads();  // prev iter's LDS reads done

        // ---- stage K hi/lo + V^T hi/lo: pre-converted bf16, 16B chunks, swizzled ----
        // K: 1024 chunks (n=cl>>4, kc8=cl&15); V^T: 1024 chunks (d=cl>>3, cc=cl&7).
        #pragma unroll
        for (int u = 0; u < 4; ++u) {
            const int cl = (wb * 4 + u) * 64 + lane;
            const int n = cl >> 4, kc8 = cl & 15;
            const size_t kg = (size_t)(c0 + n) * D_DIM + kc8 * 8;
            uint4 a0 = *(const uint4*)(KhiH + kg);
            uint4 a1 = *(const uint4*)(KloH + kg);
            const int d = cl >> 3, cc = cl & 7;
            const size_t vg = (size_t)d * SEQ + c0 + cc * 8;
            uint4 a2 = *(const uint4*)(VthiH + vg);
            uint4 a3 = *(const uint4*)(VtloH + vg);
            const int ko = n * 128 + ((kc8 ^ (n & 7)) * 8);
            const int vo = d * 64 + ((cc ^ (d & 7)) * 8);
            *(uint4*)(Khs + ko) = a0;
            *(uint4*)(Kls + ko) = a1;
            *(uint4*)(Vhs + vo) = a2;
            *(uint4*)(Vls + vo) = a3;
        }
        __syncthreads();

        if (c0 <= qrow0 + 31) {  // wave-uniform causal skip
            // ---- S = Q K^T (split-3: hh + hl + lh) ----
            f32x4 accS[2][4];
            #pragma unroll
            for (int mt = 0; mt < 2; ++mt)
                #pragma unroll
                for (int nt = 0; nt < 4; ++nt) accS[mt][nt] = (f32x4){0.f, 0.f, 0.f, 0.f};
            #pragma unroll
            for (int kc = 0; kc < 4; ++kc) {
                #pragma unroll
                for (int ntp = 0; ntp < 4; ntp += 2) {
                    Frag Bh[2], Bl[2];
                    #pragma unroll
                    for (int e2 = 0; e2 < 2; ++e2) {
                        int n = (ntp + e2) * 16 + ln;
                        int off = n * 128 + (((kc * 4 + qd) ^ (n & 7)) * 8);
                        Bh[e2].v = *(const bf16x8*)(Khs + off);
                        Bl[e2].v = *(const bf16x8*)(Kls + off);
                    }
                    #pragma unroll
                    for (int mt = 0; mt < 2; ++mt)
                        #pragma unroll
                        for (int e2 = 0; e2 < 2; ++e2) {
                            f32x4 c = accS[mt][ntp + e2];
                            c = __builtin_amdgcn_mfma_f32_16x16x32_bf16(Qh[mt][kc].v, Bh[e2].v, c, 0, 0, 0);
                            c = __builtin_amdgcn_mfma_f32_16x16x32_bf16(Qh[mt][kc].v, Bl[e2].v, c, 0, 0, 0);
                            c = __builtin_amdgcn_mfma_f32_16x16x32_bf16(Ql[mt][kc].v, Bh[e2].v, c, 0, 0, 0);
                            accS[mt][ntp + e2] = c;
                        }
                }
            }
            // ---- online softmax (exact m/l in fp32) ----
            #pragma unroll
            for (int mt = 0; mt < 2; ++mt) {
                #pragma unroll
                for (int r = 0; r < 4; ++r) {
                    const int rowg = qrow0 + mt * 16 + qd * 4 + r;
                    float sv[4], mx = -INFINITY;
                    #pragma unroll
                    for (int nt = 0; nt < 4; ++nt) {
                        float s = accS[mt][nt][r] * SCALE;
                        if (c0 + nt * 16 + ln > rowg) s = -INFINITY;  // causal
                        sv[nt] = s; mx = fmaxf(mx, s);
                    }
                    #pragma unroll
                    for (int off = 1; off < 16; off <<= 1) mx = fmaxf(mx, __shfl_xor(mx, off));
                    const float mnew = fmaxf(m_r[mt][r], mx);
                    const float alpha = __expf(m_r[mt][r] - mnew);  // first tile: exp(-inf)=0
                    float p[4], rs = 0.f;
                    #pragma unroll
                    for (int nt = 0; nt < 4; ++nt) { p[nt] = __expf(sv[nt] - mnew); rs += p[nt]; }
                    #pragma unroll
                    for (int off = 1; off < 16; off <<= 1) rs += __shfl_xor(rs, off);
                    m_r[mt][r] = mnew;
                    l_r[mt][r] = l_r[mt][r] * alpha + rs;
                    #pragma unroll
                    for (int nd = 0; nd < 8; ++nd) accO[mt][nd][r] *= alpha;
                    const int R = wb * 32 + mt * 16 + qd * 4 + r;  // intra-wave P region
                    #pragma unroll
                    for (int nt = 0; nt < 4; ++nt) {
                        int c = nt * 16 + ln;
                        Pbs[R * 64 + (((c >> 3) ^ (R & 7)) * 8) + (c & 7)] = bf16_rne(p[nt]);
                    }
                }
            }
            // ---- O += P (V_hi + V_lo) ----
            #pragma unroll
            for (int kc2 = 0; kc2 < 2; ++kc2) {
                Frag Pf[2];
                #pragma unroll
                for (int mt = 0; mt < 2; ++mt) {
                    int R = wb * 32 + mt * 16 + ln;
                    Pf[mt].v = *(const bf16x8*)(Pbs + R * 64 + (((kc2 * 4 + qd) ^ (R & 7)) * 8));
                }
                #pragma unroll
                for (int nd = 0; nd < 8; ++nd) {
                    int dcol = nd * 16 + ln;
                    int voff = dcol * 64 + (((kc2 * 4 + qd) ^ (dcol & 7)) * 8);
                    Frag Vh2, Vl2;
                    Vh2.v = *(const bf16x8*)(Vhs + voff);
                    Vl2.v = *(const bf16x8*)(Vls + voff);
                    #pragma unroll
                    for (int mt = 0; mt < 2; ++mt) {
                        f32x4 c = accO[mt][nd];
                        c = __builtin_amdgcn_mfma_f32_16x16x32_bf16(Pf[mt].v, Vh2.v, c, 0, 0, 0);
                        c = __builtin_amdgcn_mfma_f32_16x16x32_bf16(Pf[mt].v, Vl2.v, c, 0, 0, 0);
                        accO[mt][nd] = c;
                    }
                }
            }
        }
    }

    // ---- epilogue: O/l, stats tiled x8 ----
    #pragma unroll
    for (int mt = 0; mt < 2; ++mt) {
        #pragma unroll
        for (int r = 0; r < 4; ++r) {
            const int rowg = qrow0 + mt * 16 + qd * 4 + r;
            const float invl = 1.0f / l_r[mt][r];
            float* op = out_o + (size_t)h * SEQ * D_DIM + (size_t)rowg * D_DIM;
            #pragma unroll
            for (int nd = 0; nd < 8; ++nd) op[nd * 16 + ln] = accO[mt][nd][r] * invl;
            if (ln < 8) {
                size_t sb = ((size_t)h * SEQ + rowg) * 8 + ln;
                out_m[sb] = m_r[mt][r];
                out_l[sb] = l_r[mt][r];
            }
        }
    }
}

// ---------------- fallback (proven R3 kernel, used only if ws too small) ----------------
__global__ __launch_bounds__(256, 2) void fa_fwd_fb(
    const float* __restrict__ q, const float* __restrict__ k,
    const float* __restrict__ v, float* __restrict__ out)
{
    __shared__ __align__(16) unsigned short Khs[64 * 128];
    __shared__ __align__(16) unsigned short Kls[64 * 128];
    __shared__ __align__(16) unsigned short Vhs[128 * 64];
    __shared__ __align__(16) unsigned short Vls[128 * 64];
    __shared__ __align__(16) unsigned short Pbs[128 * 64];

    const int x = blockIdx.x;
    const int y = x >> 3;
    const int s_idx = y & 15;
    const int h = (x & 7) * 4 + (y >> 4);
    const int it = (y < 32) ? (15 - s_idx) : s_idx;

    const int t = (int)threadIdx.x;
    const int wb = t >> 6, lane = t & 63, ln = lane & 15, qd = lane >> 4;

    const float* qh = q + (size_t)h * SEQ * D_DIM;
    const float* kh = k + (size_t)h * SEQ * D_DIM;
    const float* vh = v + (size_t)h * SEQ * D_DIM;
    float* out_o = out;
    float* out_m = out + (size_t)NHEADS * SEQ * D_DIM;
    float* out_l = out_m + (size_t)NHEADS * SEQ * 8;

    const int qrow0 = it * BR + wb * 32;

    Frag Qh[2][4], Ql[2][4];
    #pragma unroll
    for (int mt = 0; mt < 2; ++mt) {
        const float* qp = qh + (size_t)(qrow0 + mt * 16 + ln) * D_DIM;
        #pragma unroll
        for (int kc = 0; kc < 4; ++kc) {
            const int kb = kc * 32 + qd * 8;
            float e[8];
            *(float4*)(e)     = *(const float4*)(qp + kb);
            *(float4*)(e + 4) = *(const float4*)(qp + kb + 4);
            #pragma unroll
            for (int j = 0; j < 4; ++j)
                split2(e[2 * j], e[2 * j + 1], Qh[mt][kc].u[j], Ql[mt][kc].u[j]);
        }
    }

    f32x4 accO[2][8];
    float m_r[2][4], l_r[2][4];
    #pragma unroll
    for (int mt = 0; mt < 2; ++mt) {
        #pragma unroll
        for (int nd = 0; nd < 8; ++nd) accO[mt][nd] = (f32x4){0.f, 0.f, 0.f, 0.f};
        #pragma unroll
        for (int r = 0; r < 4; ++r) { m_r[mt][r] = -INFINITY; l_r[mt][r] = 0.f; }
    }

    const int jt_end = 2 * it + 1;
    for (int jt = 0; jt <= jt_end; ++jt) {
        const int c0 = jt * BC;
        __syncthreads();
        #pragma unroll
        for (int itr = 0; itr < 8; ++itr) {
            int f = itr * 256 + t;
            int row = f >> 5, d4 = f & 31;
            float e[4];
            *(float4*)e = *(const float4*)(kh + (size_t)(c0 + row) * D_DIM + d4 * 4);
            uint32_t hp[2], lp[2];
            split2(e[0], e[1], hp[0], lp[0]);
            split2(e[2], e[3], hp[1], lp[1]);
            int off = row * 128 + (((d4 >> 1) ^ (row & 7)) * 8) + (d4 & 1) * 4;
            *(uint2*)(Khs + off) = make_uint2(hp[0], hp[1]);
            *(uint2*)(Kls + off) = make_uint2(lp[0], lp[1]);
        }
        #pragma unroll
        for (int uu = 0; uu < 4; ++uu) {
            int ug = wb * 4 + uu;
            int cc = ug >> 1, dh = ug & 1;
            int d = dh * 64 + lane;
            Frag fh, fl;
            #pragma unroll
            for (int j = 0; j < 8; j += 2) {
                float a = vh[(size_t)(c0 + cc * 8 + j) * D_DIM + d];
                float b = vh[(size_t)(c0 + cc * 8 + j + 1) * D_DIM + d];
                split2(a, b, fh.u[j >> 1], fl.u[j >> 1]);
            }
            int off = d * 64 + ((cc ^ (d & 7)) * 8);
            *(bf16x8*)(Vhs + off) = fh.v;
            *(bf16x8*)(Vls + off) = fl.v;
        }
        __syncthreads();

        if (c0 <= qrow0 + 31) {
            f32x4 accS[2][4];
            #pragma unroll
            for (int mt = 0; mt < 2; ++mt)
                #pragma unroll
                for (int nt = 0; nt < 4; ++nt) accS[mt][nt] = (f32x4){0.f, 0.f, 0.f, 0.f};
            #pragma unroll
            for (int kc = 0; kc < 4; ++kc) {
                #pragma unroll
                for (int ntp = 0; ntp < 4; ntp += 2) {
                    Frag Bh[2], Bl[2];
                    #pragma unroll
                    for (int e2 = 0; e2 < 2; ++e2) {
                        int n = (ntp + e2) * 16 + ln;
                        int off = n * 128 + (((kc * 4 + qd) ^ (n & 7)) * 8);
                        Bh[e2].v = *(const bf16x8*)(Khs + off);
                        Bl[e2].v = *(const bf16x8*)(Kls + off);
                    }
                    #pragma unroll
                    for (int mt = 0; mt < 2; ++mt)
                        #pragma unroll
                        for (int e2 = 0; e2 < 2; ++e2) {
                            f32x4 c = accS[mt][ntp + e2];
                            c = __builtin_amdgcn_mfma_f32_16x16x32_bf16(Qh[mt][kc].v, Bh[e2].v, c, 0, 0, 0);
                            c = __builtin_amdgcn_mfma_f32_16x16x32_bf16(Qh[mt][kc].v, Bl[e2].v, c, 0, 0, 0);
                            c = __builtin_amdgcn_mfma_f32_16x16x32_bf16(Ql[mt][kc].v, Bh[e2].v, c, 0, 0, 0);
                            accS[mt][ntp + e2] = c;
                        }
                }
            }
            #pragma unroll
            for (int mt = 0; mt < 2; ++mt) {
                #pragma unroll
                for (int r = 0; r < 4; ++r) {
                    const int rowg = qrow0 + mt * 16 + qd * 4 + r;
                    float sv[4], mx = -INFINITY;
                    #pragma unroll
                    for (int nt = 0; nt < 4; ++nt) {
                        float s = accS[mt][nt][r] * SCALE;
                        if (c0 + nt * 16 + ln > rowg) s = -INFINITY;
                        sv[nt] = s; mx = fmaxf(mx, s);
                    }
                    #pragma unroll
                    for (int off = 1; off < 16; off <<= 1) mx = fmaxf(mx, __shfl_xor(mx, off));
                    const float mnew = fmaxf(m_r[mt][r], mx);
                    const float alpha = __expf(m_r[mt][r] - mnew);
                    float p[4], rs = 0.f;
                    #pragma unroll
                    for (int nt = 0; nt < 4; ++nt) { p[nt] = __expf(sv[nt] - mnew); rs += p[nt]; }
                    #pragma unroll
                    for (int off = 1; off < 16; off <<= 1) rs += __shfl_xor(rs, off);
                    m_r[mt][r] = mnew;
                    l_r[mt][r] = l_r[mt][r] * alpha + rs;
                    #pragma unroll
                    for (int nd = 0; nd < 8; ++nd) accO[mt][nd][r] *= alpha;
                    const int R = wb * 32 + mt * 16 + qd * 4 + r;
                    #pragma unroll
                    for (int nt = 0; nt < 4; ++nt) {
                        int c = nt * 16 + ln;
                        Pbs[R * 64 + (((c >> 3) ^ (R & 7)) * 8) + (c & 7)] = bf16_rne(p[nt]);
                    }
                }
            }
            #pragma unroll
            for (int kc2 = 0; kc2 < 2; ++kc2) {
                Frag Pf[2];
                #pragma unroll
                for (int mt = 0; mt < 2; ++mt) {
                    int R = wb * 32 + mt * 16 + ln;
                    Pf[mt].v = *(const bf16x8*)(Pbs + R * 64 + (((kc2 * 4 + qd) ^ (R & 7)) * 8));
                }
                #pragma unroll
                for (int nd = 0; nd < 8; ++nd) {
                    int dcol = nd * 16 + ln;
                    int voff = dcol * 64 + (((kc2 * 4 + qd) ^ (dcol & 7)) * 8);
                    Frag Vh2, Vl2;
                    Vh2.v = *(const bf16x8*)(Vhs + voff);
                    Vl2.v = *(const bf16x8*)(Vls + voff);
                    #pragma unroll
                    for (int mt = 0; mt < 2; ++mt) {
                        f32x4 c = accO[mt][nd];
                        c = __builtin_amdgcn_mfma_f32_16x16x32_bf16(Pf[mt].v, Vh2.v, c, 0, 0, 0);
                        c = __builtin_amdgcn_mfma_f32_16x16x32_bf16(Pf[mt].v, Vl2.v, c, 0, 0, 0);
                        accO[mt][nd] = c;
                    }
                }
            }
        }
    }

    #pragma unroll
    for (int mt = 0; mt < 2; ++mt) {
        #pragma unroll
        for (int r = 0; r < 4; ++r) {
            const int rowg = qrow0 + mt * 16 + qd * 4 + r;
            const float invl = 1.0f / l_r[mt][r];
            float* op = out_o + (size_t)h * SEQ * D_DIM + (size_t)rowg * D_DIM;
            #pragma unroll
            for (int nd = 0; nd < 8; ++nd) op[nd * 16 + ln] = accO[mt][nd][r] * invl;
            if (ln < 8) {
                size_t sb = ((size_t)h * SEQ + rowg) * 8 + ln;
                out_m[sb] = m_r[mt][r];
                out_l[sb] = l_r[mt][r];
            }
        }
    }
}

extern "C" void kernel_launch(void* const* d_in, const int* in_sizes, int n_in,
                              void* d_out, int out_size, void* d_ws, size_t ws_size,
                              hipStream_t stream) {
    const float* q = (const float*)d_in[0];
    const float* k = (const float*)d_in[1];
    const float* v = (const float*)d_in[2];
    float* out = (float*)d_out;

    const size_t N = (size_t)NHEADS * SEQ * D_DIM;  // 8388608 elements
    const size_t need = 4 * N * sizeof(unsigned short);  // 67,108,864 B
    if (ws_size >= need) {
        unsigned short* Khi = (unsigned short*)d_ws;
        unsigned short* Klo = Khi + N;
        unsigned short* Vthi = Klo + N;
        unsigned short* Vtlo = Vthi + N;
        cvt_kv<<<dim3(8192 + 2048), dim3(256), 0, stream>>>(k, v, Khi, Klo, Vthi, Vtlo);
        fa_fwd2<<<dim3(512), dim3(256), 0, stream>>>(q, Khi, Klo, Vthi, Vtlo, out);
    } else {
        fa_fwd_fb<<<dim3(512), dim3(256), 0, stream>>>(q, k, v, out);
    }
}

// Round 5
// 246.176 us; speedup vs baseline: 4.2279x; 2.0428x over previous
//
#include <hip/hip_runtime.h>
#include <math.h>
#include <stdint.h>

#define D_DIM 128
#define SEQ 2048
#define NHEADS 32
#define BC 64
#define SCALE 0.08838834764831843f  // 1/sqrt(128)
#define IMG_U16 24576               // per-(h,jt) tile image: Khi 8192 | Klo 8192 | Vhi 8192 u16

typedef short bf16x8 __attribute__((ext_vector_type(8)));
typedef float f32x4 __attribute__((ext_vector_type(4)));

union Frag { uint32_t u[4]; bf16x8 v; unsigned short s[8]; };
union Pack8 { unsigned short s[8]; uint4 q; };

__device__ __forceinline__ uint32_t fbits(float x) { return __builtin_bit_cast(uint32_t, x); }
__device__ __forceinline__ float bbits(uint32_t u) { return __builtin_bit_cast(float, u); }
__device__ __forceinline__ unsigned short bf16_rne(float x) {
    uint32_t u = fbits(x);
    u += 0x7FFFu + ((u >> 16) & 1u);
    return (unsigned short)(u >> 16);
}
// hi = truncate-to-bf16(x) (exact residual), lo = bf16(x - hi). even->low16, odd->high16.
__device__ __forceinline__ void split2(float a, float b, uint32_t& hp, uint32_t& lp) {
    uint32_t ua = fbits(a) & 0xFFFF0000u, ub = fbits(b) & 0xFFFF0000u;
    float la = a - bbits(ua), lb = b - bbits(ub);
    hp = (ua >> 16) | ub;
    lp = (fbits(la) >> 16) | (fbits(lb) & 0xFFFF0000u);
}

// async global->LDS, 16B per lane; lds addr must be wave-uniform (lane*16 is implicit).
__device__ __forceinline__ void gl_lds16(const unsigned short* g, unsigned short* l) {
    __builtin_amdgcn_global_load_lds(
        (const __attribute__((address_space(1))) uint32_t*)g,
        (__attribute__((address_space(3))) uint32_t*)l, 16, 0, 0);
}

// ---------------- pre-pass: build pre-swizzled LDS tile images in ws ----------------
// Image layout (u16): Khi[n*128 + ((kc8^(n&7))*8)] (n=0..63 row, kc8=0..15 k-chunk of 8),
//                     Klo at +8192, Vhi[d*64 + ((cc^(d&7))*8)] at +16384 (d=0..127, cc=0..7 s-chunk).
__global__ __launch_bounds__(256) void cvt_kv(
    const float* __restrict__ k, const float* __restrict__ v, unsigned short* __restrict__ ws)
{
    const int b = blockIdx.x;              // 1024 = 32 heads x 32 jt
    const int h = b >> 5, jt = b & 31;
    const int t = (int)threadIdx.x;
    unsigned short* img = ws + (size_t)b * IMG_U16;
    const float* kp = k + ((size_t)h * SEQ + jt * 64) * D_DIM;
    const float* vp = v + ((size_t)h * SEQ + jt * 64) * D_DIM;

    #pragma unroll
    for (int u = 0; u < 4; ++u) {          // K: 1024 chunks of 8 floats
        int idx = u * 256 + t;
        int n = idx >> 4, kc8 = idx & 15;
        float e[8];
        *(float4*)(e)     = *(const float4*)(kp + (size_t)n * D_DIM + kc8 * 8);
        *(float4*)(e + 4) = *(const float4*)(kp + (size_t)n * D_DIM + kc8 * 8 + 4);
        uint32_t hp[4], lp[4];
        #pragma unroll
        for (int j = 0; j < 4; ++j) split2(e[2 * j], e[2 * j + 1], hp[j], lp[j]);
        int off = n * 128 + ((kc8 ^ (n & 7)) * 8);
        *(uint4*)(img + off)        = make_uint4(hp[0], hp[1], hp[2], hp[3]);
        *(uint4*)(img + 8192 + off) = make_uint4(lp[0], lp[1], lp[2], lp[3]);
    }
    #pragma unroll
    for (int u = 0; u < 4; ++u) {          // V^T: 1024 chunks (d, cc), RNE bf16 (no lo)
        int idx = u * 256 + t;
        int d = idx >> 3, cc = idx & 7;
        Pack8 p8;
        #pragma unroll
        for (int j = 0; j < 8; ++j)
            p8.s[j] = bf16_rne(vp[(size_t)(cc * 8 + j) * D_DIM + d]);
        int off = d * 64 + ((cc ^ (d & 7)) * 8);
        *(uint4*)(img + 16384 + off) = p8.q;
    }
}

// ---------------- attention: 512 thr = 8 waves x 16 q-rows; double-buffered DMA staging ----------------
// 16x16x32 bf16 MFMA; layouts: A[m=lane&15][k=quad*8+j], B[k=quad*8+j][n=lane&15],
// C/D[row=quad*4+reg][col=lane&15].
__global__ __launch_bounds__(512, 2) void fa_fwd3(
    const float* __restrict__ q, const unsigned short* __restrict__ ws, float* __restrict__ out)
{
    __shared__ __align__(16) unsigned short Stage[2][IMG_U16];  // 2 x 48KB
    __shared__ __align__(16) unsigned short Pbs[128 * 64];      // 16KB -> 112KB total, 1 block/CU

    // LPT order: heavy q-tiles dispatch first; dynamic dispatch balances CUs.
    const int x = blockIdx.x;
    const int it = 15 - (x >> 5);
    const int h = x & 31;

    const int t    = (int)threadIdx.x;
    const int wb   = t >> 6;
    const int lane = t & 63;
    const int ln   = lane & 15;
    const int qd   = lane >> 4;

    const unsigned short* wsh = ws + (size_t)(h * 32) * IMG_U16;
    float* out_o = out;
    float* out_m = out + (size_t)NHEADS * SEQ * D_DIM;
    float* out_l = out_m + (size_t)NHEADS * SEQ * 8;

    const int qrow0 = it * 128 + wb * 16;

    // prologue: stage tile 0 into Stage[0] (fire-and-forget, 6 x 1KB per wave)
    {
        const unsigned short* g = wsh + wb * 3072 + lane * 8;
        unsigned short* l = &Stage[0][wb * 3072];
        #pragma unroll
        for (int i = 0; i < 6; ++i) gl_lds16(g + i * 512, l + i * 512);
    }

    // Q fragments (exact hi/lo split) in registers: 32 VGPRs
    Frag Qh[4], Ql[4];
    {
        const float* qp = q + ((size_t)h * SEQ + qrow0 + ln) * D_DIM;
        #pragma unroll
        for (int kc = 0; kc < 4; ++kc) {
            const int kb = kc * 32 + qd * 8;
            float e[8];
            *(float4*)(e)     = *(const float4*)(qp + kb);
            *(float4*)(e + 4) = *(const float4*)(qp + kb + 4);
            #pragma unroll
            for (int j = 0; j < 4; ++j)
                split2(e[2 * j], e[2 * j + 1], Qh[kc].u[j], Ql[kc].u[j]);
        }
    }

    f32x4 accO[8];
    float m_r[4], l_r[4];
    #pragma unroll
    for (int nd = 0; nd < 8; ++nd) accO[nd] = (f32x4){0.f, 0.f, 0.f, 0.f};
    #pragma unroll
    for (int r = 0; r < 4; ++r) { m_r[r] = -INFINITY; l_r[r] = 0.f; }

    const int jt_end = 2 * it + 1;
    for (int jt = 0; jt <= jt_end; ++jt) {
        const int c0 = jt * BC;
        __syncthreads();  // drains vmcnt: Stage[jt&1] complete; prev reads of Stage[1-jt&1] done

        if (jt < jt_end) {  // prefetch next tile into the other buffer (overlaps compute)
            const unsigned short* g = wsh + (size_t)(jt + 1) * IMG_U16 + wb * 3072 + lane * 8;
            unsigned short* l = &Stage[(jt + 1) & 1][wb * 3072];
            #pragma unroll
            for (int i = 0; i < 6; ++i) gl_lds16(g + i * 512, l + i * 512);
        }

        const unsigned short* Khs = Stage[jt & 1];
        const unsigned short* Kls = Khs + 8192;
        const unsigned short* Vhs = Khs + 16384;

        if (c0 <= qrow0 + 15) {  // wave-uniform causal skip
            // ---- S = Q K^T (split-3: hh + hl + lh), 48 MFMAs ----
            f32x4 accS[4];
            #pragma unroll
            for (int nt = 0; nt < 4; ++nt) accS[nt] = (f32x4){0.f, 0.f, 0.f, 0.f};
            #pragma unroll
            for (int kc = 0; kc < 4; ++kc) {
                #pragma unroll
                for (int nt = 0; nt < 4; ++nt) {
                    int n = nt * 16 + ln;
                    int off = n * 128 + (((kc * 4 + qd) ^ (n & 7)) * 8);
                    Frag Bh, Bl;
                    Bh.v = *(const bf16x8*)(Khs + off);
                    Bl.v = *(const bf16x8*)(Kls + off);
                    f32x4 c = accS[nt];
                    c = __builtin_amdgcn_mfma_f32_16x16x32_bf16(Qh[kc].v, Bh.v, c, 0, 0, 0);
                    c = __builtin_amdgcn_mfma_f32_16x16x32_bf16(Qh[kc].v, Bl.v, c, 0, 0, 0);
                    c = __builtin_amdgcn_mfma_f32_16x16x32_bf16(Ql[kc].v, Bh.v, c, 0, 0, 0);
                    accS[nt] = c;
                }
            }
            // ---- online softmax (exact m/l in fp32) ----
            #pragma unroll
            for (int r = 0; r < 4; ++r) {
                const int rowg = qrow0 + qd * 4 + r;
                float sv[4], mx = -INFINITY;
                #pragma unroll
                for (int nt = 0; nt < 4; ++nt) {
                    float s = accS[nt][r] * SCALE;
                    if (c0 + nt * 16 + ln > rowg) s = -INFINITY;  // causal
                    sv[nt] = s; mx = fmaxf(mx, s);
                }
                #pragma unroll
                for (int off = 1; off < 16; off <<= 1) mx = fmaxf(mx, __shfl_xor(mx, off));
                const float mnew = fmaxf(m_r[r], mx);
                const float alpha = __expf(m_r[r] - mnew);  // first live tile: exp(-inf)=0
                float p[4], rs = 0.f;
                #pragma unroll
                for (int nt = 0; nt < 4; ++nt) { p[nt] = __expf(sv[nt] - mnew); rs += p[nt]; }
                #pragma unroll
                for (int off = 1; off < 16; off <<= 1) rs += __shfl_xor(rs, off);
                m_r[r] = mnew;
                l_r[r] = l_r[r] * alpha + rs;
                #pragma unroll
                for (int nd = 0; nd < 8; ++nd) accO[nd][r] *= alpha;
                const int R = wb * 16 + qd * 4 + r;  // intra-wave P region
                #pragma unroll
                for (int nt = 0; nt < 4; ++nt) {
                    int c = nt * 16 + ln;
                    Pbs[R * 64 + (((c >> 3) ^ (R & 7)) * 8) + (c & 7)] = bf16_rne(p[nt]);
                }
            }
            // ---- O += P V_hi, 16 MFMAs ----
            #pragma unroll
            for (int kc2 = 0; kc2 < 2; ++kc2) {
                Frag Pf;
                const int R = wb * 16 + ln;
                Pf.v = *(const bf16x8*)(Pbs + R * 64 + (((kc2 * 4 + qd) ^ (R & 7)) * 8));
                #pragma unroll
                for (int nd = 0; nd < 8; ++nd) {
                    int dcol = nd * 16 + ln;
                    int voff = dcol * 64 + (((kc2 * 4 + qd) ^ (dcol & 7)) * 8);
                    Frag Vh2;
                    Vh2.v = *(const bf16x8*)(Vhs + voff);
                    accO[nd] = __builtin_amdgcn_mfma_f32_16x16x32_bf16(Pf.v, Vh2.v, accO[nd], 0, 0, 0);
                }
            }
        }
    }

    // ---- epilogue: O/l, stats tiled x8 ----
    #pragma unroll
    for (int r = 0; r < 4; ++r) {
        const int rowg = qrow0 + qd * 4 + r;
        const float invl = 1.0f / l_r[r];
        float* op = out_o + (size_t)h * SEQ * D_DIM + (size_t)rowg * D_DIM;
        #pragma unroll
        for (int nd = 0; nd < 8; ++nd) op[nd * 16 + ln] = accO[nd][r] * invl;
        if (ln < 8) {
            size_t sb = ((size_t)h * SEQ + rowg) * 8 + ln;
            out_m[sb] = m_r[r];
            out_l[sb] = l_r[r];
        }
    }
}

// ---------------- fallback (proven R3/R4 kernel, used only if ws too small) ----------------
__global__ __launch_bounds__(256, 2) void fa_fwd_fb(
    const float* __restrict__ q, const float* __restrict__ k,
    const float* __restrict__ v, float* __restrict__ out)
{
    __shared__ __align__(16) unsigned short Khs[64 * 128];
    __shared__ __align__(16) unsigned short Kls[64 * 128];
    __shared__ __align__(16) unsigned short Vhs[128 * 64];
    __shared__ __align__(16) unsigned short Vls[128 * 64];
    __shared__ __align__(16) unsigned short Pbs[128 * 64];

    const int x = blockIdx.x;
    const int y = x >> 3;
    const int s_idx = y & 15;
    const int h = (x & 7) * 4 + (y >> 4);
    const int it = (y < 32) ? (15 - s_idx) : s_idx;

    const int t = (int)threadIdx.x;
    const int wb = t >> 6, lane = t & 63, ln = lane & 15, qd = lane >> 4;

    const float* qh = q + (size_t)h * SEQ * D_DIM;
    const float* kh = k + (size_t)h * SEQ * D_DIM;
    const float* vh = v + (size_t)h * SEQ * D_DIM;
    float* out_o = out;
    float* out_m = out + (size_t)NHEADS * SEQ * D_DIM;
    float* out_l = out_m + (size_t)NHEADS * SEQ * 8;

    const int qrow0 = it * 128 + wb * 32;

    Frag Qh[2][4], Ql[2][4];
    #pragma unroll
    for (int mt = 0; mt < 2; ++mt) {
        const float* qp = qh + (size_t)(qrow0 + mt * 16 + ln) * D_DIM;
        #pragma unroll
        for (int kc = 0; kc < 4; ++kc) {
            const int kb = kc * 32 + qd * 8;
            float e[8];
            *(float4*)(e)     = *(const float4*)(qp + kb);
            *(float4*)(e + 4) = *(const float4*)(qp + kb + 4);
            #pragma unroll
            for (int j = 0; j < 4; ++j)
                split2(e[2 * j], e[2 * j + 1], Qh[mt][kc].u[j], Ql[mt][kc].u[j]);
        }
    }

    f32x4 accO[2][8];
    float m_r[2][4], l_r[2][4];
    #pragma unroll
    for (int mt = 0; mt < 2; ++mt) {
        #pragma unroll
        for (int nd = 0; nd < 8; ++nd) accO[mt][nd] = (f32x4){0.f, 0.f, 0.f, 0.f};
        #pragma unroll
        for (int r = 0; r < 4; ++r) { m_r[mt][r] = -INFINITY; l_r[mt][r] = 0.f; }
    }

    const int jt_end = 2 * it + 1;
    for (int jt = 0; jt <= jt_end; ++jt) {
        const int c0 = jt * BC;
        __syncthreads();
        #pragma unroll
        for (int itr = 0; itr < 8; ++itr) {
            int f = itr * 256 + t;
            int row = f >> 5, d4 = f & 31;
            float e[4];
            *(float4*)e = *(const float4*)(kh + (size_t)(c0 + row) * D_DIM + d4 * 4);
            uint32_t hp[2], lp[2];
            split2(e[0], e[1], hp[0], lp[0]);
            split2(e[2], e[3], hp[1], lp[1]);
            int off = row * 128 + (((d4 >> 1) ^ (row & 7)) * 8) + (d4 & 1) * 4;
            *(uint2*)(Khs + off) = make_uint2(hp[0], hp[1]);
            *(uint2*)(Kls + off) = make_uint2(lp[0], lp[1]);
        }
        #pragma unroll
        for (int uu = 0; uu < 4; ++uu) {
            int ug = wb * 4 + uu;
            int cc = ug >> 1, dh = ug & 1;
            int d = dh * 64 + lane;
            Frag fh, fl;
            #pragma unroll
            for (int j = 0; j < 8; j += 2) {
                float a = vh[(size_t)(c0 + cc * 8 + j) * D_DIM + d];
                float b = vh[(size_t)(c0 + cc * 8 + j + 1) * D_DIM + d];
                split2(a, b, fh.u[j >> 1], fl.u[j >> 1]);
            }
            int off = d * 64 + ((cc ^ (d & 7)) * 8);
            *(bf16x8*)(Vhs + off) = fh.v;
            *(bf16x8*)(Vls + off) = fl.v;
        }
        __syncthreads();

        if (c0 <= qrow0 + 31) {
            f32x4 accS[2][4];
            #pragma unroll
            for (int mt = 0; mt < 2; ++mt)
                #pragma unroll
                for (int nt = 0; nt < 4; ++nt) accS[mt][nt] = (f32x4){0.f, 0.f, 0.f, 0.f};
            #pragma unroll
            for (int kc = 0; kc < 4; ++kc) {
                #pragma unroll
                for (int ntp = 0; ntp < 4; ntp += 2) {
                    Frag Bh[2], Bl[2];
                    #pragma unroll
                    for (int e2 = 0; e2 < 2; ++e2) {
                        int n = (ntp + e2) * 16 + ln;
                        int off = n * 128 + (((kc * 4 + qd) ^ (n & 7)) * 8);
                        Bh[e2].v = *(const bf16x8*)(Khs + off);
                        Bl[e2].v = *(const bf16x8*)(Kls + off);
                    }
                    #pragma unroll
                    for (int mt = 0; mt < 2; ++mt)
                        #pragma unroll
                        for (int e2 = 0; e2 < 2; ++e2) {
                            f32x4 c = accS[mt][ntp + e2];
                            c = __builtin_amdgcn_mfma_f32_16x16x32_bf16(Qh[mt][kc].v, Bh[e2].v, c, 0, 0, 0);
                            c = __builtin_amdgcn_mfma_f32_16x16x32_bf16(Qh[mt][kc].v, Bl[e2].v, c, 0, 0, 0);
                            c = __builtin_amdgcn_mfma_f32_16x16x32_bf16(Ql[mt][kc].v, Bh[e2].v, c, 0, 0, 0);
                            accS[mt][ntp + e2] = c;
                        }
                }
            }
            #pragma unroll
            for (int mt = 0; mt < 2; ++mt) {
                #pragma unroll
                for (int r = 0; r < 4; ++r) {
                    const int rowg = qrow0 + mt * 16 + qd * 4 + r;
                    float sv[4], mx = -INFINITY;
                    #pragma unroll
                    for (int nt = 0; nt < 4; ++nt) {
                        float s = accS[mt][nt][r] * SCALE;
                        if (c0 + nt * 16 + ln > rowg) s = -INFINITY;
                        sv[nt] = s; mx = fmaxf(mx, s);
                    }
                    #pragma unroll
                    for (int off = 1; off < 16; off <<= 1) mx = fmaxf(mx, __shfl_xor(mx, off));
                    const float mnew = fmaxf(m_r[mt][r], mx);
                    const float alpha = __expf(m_r[mt][r] - mnew);
                    float p[4], rs = 0.f;
                    #pragma unroll
                    for (int nt = 0; nt < 4; ++nt) { p[nt] = __expf(sv[nt] - mnew); rs += p[nt]; }
                    #pragma unroll
                    for (int off = 1; off < 16; off <<= 1) rs += __shfl_xor(rs, off);
                    m_r[mt][r] = mnew;
                    l_r[mt][r] = l_r[mt][r] * alpha + rs;
                    #pragma unroll
                    for (int nd = 0; nd < 8; ++nd) accO[mt][nd][r] *= alpha;
                    const int R = wb * 32 + mt * 16 + qd * 4 + r;
                    #pragma unroll
                    for (int nt = 0; nt < 4; ++nt) {
                        int c = nt * 16 + ln;
                        Pbs[R * 64 + (((c >> 3) ^ (R & 7)) * 8) + (c & 7)] = bf16_rne(p[nt]);
                    }
                }
            }
            #pragma unroll
            for (int kc2 = 0; kc2 < 2; ++kc2) {
                Frag Pf[2];
                #pragma unroll
                for (int mt = 0; mt < 2; ++mt) {
                    int R = wb * 32 + mt * 16 + ln;
                    Pf[mt].v = *(const bf16x8*)(Pbs + R * 64 + (((kc2 * 4 + qd) ^ (R & 7)) * 8));
                }
                #pragma unroll
                for (int nd = 0; nd < 8; ++nd) {
                    int dcol = nd * 16 + ln;
                    int voff = dcol * 64 + (((kc2 * 4 + qd) ^ (dcol & 7)) * 8);
                    Frag Vh2, Vl2;
                    Vh2.v = *(const bf16x8*)(Vhs + voff);
                    Vl2.v = *(const bf16x8*)(Vls + voff);
                    #pragma unroll
                    for (int mt = 0; mt < 2; ++mt) {
                        f32x4 c = accO[mt][nd];
                        c = __builtin_amdgcn_mfma_f32_16x16x32_bf16(Pf[mt].v, Vh2.v, c, 0, 0, 0);
                        c = __builtin_amdgcn_mfma_f32_16x16x32_bf16(Pf[mt].v, Vl2.v, c, 0, 0, 0);
                        accO[mt][nd] = c;
                    }
                }
            }
        }
    }

    #pragma unroll
    for (int mt = 0; mt < 2; ++mt) {
        #pragma unroll
        for (int r = 0; r < 4; ++r) {
            const int rowg = qrow0 + mt * 16 + qd * 4 + r;
            const float invl = 1.0f / l_r[mt][r];
            float* op = out_o + (size_t)h * SEQ * D_DIM + (size_t)rowg * D_DIM;
            #pragma unroll
            for (int nd = 0; nd < 8; ++nd) op[nd * 16 + ln] = accO[mt][nd][r] * invl;
            if (ln < 8) {
                size_t sb = ((size_t)h * SEQ + rowg) * 8 + ln;
                out_m[sb] = m_r[mt][r];
                out_l[sb] = l_r[mt][r];
            }
        }
    }
}

extern "C" void kernel_launch(void* const* d_in, const int* in_sizes, int n_in,
                              void* d_out, int out_size, void* d_ws, size_t ws_size,
                              hipStream_t stream) {
    const float* q = (const float*)d_in[0];
    const float* k = (const float*)d_in[1];
    const float* v = (const float*)d_in[2];
    float* out = (float*)d_out;

    const size_t need = (size_t)1024 * IMG_U16 * sizeof(unsigned short);  // 48 MB
    if (ws_size >= need) {
        unsigned short* ws = (unsigned short*)d_ws;
        cvt_kv<<<dim3(1024), dim3(256), 0, stream>>>(k, v, ws);
        fa_fwd3<<<dim3(512), dim3(512), 0, stream>>>(q, ws, out);
    } else {
        fa_fwd_fb<<<dim3(512), dim3(256), 0, stream>>>(q, k, v, out);
    }
}